// Round 2
// baseline (124.467 us; speedup 1.0000x reference)
//
#include <hip/hip_runtime.h>
#include <hip/hip_bf16.h>

#define NN 8192
#define DD 128
#define NCLS 100

typedef short bf16x8v __attribute__((ext_vector_type(8)));
typedef float f32x4  __attribute__((ext_vector_type(4)));

constexpr float SCALE2  = 14.426950408889634f; // (1/T) * log2(e)
constexpr float SSCALE  = 3.7982825265208916f; // sqrt(SCALE2)
constexpr float LN2     = 0.6931471805599453f;
constexpr float NEG_BIG = -1.0e30f;
constexpr float M_INIT  = -3.0e38f;

// ---------------- kernel 1: fp32 -> bf16 (RNE), pre-scaled by sqrt(SCALE2) ----------------
__global__ __launch_bounds__(256) void k_convert(const float* __restrict__ z,
                                                 unsigned short* __restrict__ zb) {
  int i = blockIdx.x * blockDim.x + threadIdx.x; // one float4 per thread
  const float4 v = reinterpret_cast<const float4*>(z)[i];
  auto cvt = [](float f) -> unsigned short {
    unsigned u = __float_as_uint(f);
    unsigned r = (u + 0x7fffu + ((u >> 16) & 1u)) >> 16;
    return (unsigned short)r;
  };
  ushort4 o;
  o.x = cvt(v.x * SSCALE); o.y = cvt(v.y * SSCALE);
  o.z = cvt(v.z * SSCALE); o.w = cvt(v.w * SSCALE);
  reinterpret_cast<ushort4*>(zb)[i] = o;
}

// ---------------- class sums (for exact fp32 con/cnt) ----------------
// grid (NCLS, 8): block c sums z rows with label c over a 1024-row chunk.
__global__ __launch_bounds__(128) void k_csum(const float* __restrict__ z,
                                              const int* __restrict__ labels,
                                              float* __restrict__ Cpart,
                                              float* __restrict__ cntPart) {
  const int c = blockIdx.x, chunk = blockIdx.y, d = threadIdx.x;
  const int j0 = chunk * 1024;
  float acc = 0.f; int cnt = 0;
  for (int j = j0; j < j0 + 1024; j += 4) {
    int4 lj = *reinterpret_cast<const int4*>(labels + j);
    if (lj.x == c) { acc += z[(j + 0) * DD + d]; ++cnt; }
    if (lj.y == c) { acc += z[(j + 1) * DD + d]; ++cnt; }
    if (lj.z == c) { acc += z[(j + 2) * DD + d]; ++cnt; }
    if (lj.w == c) { acc += z[(j + 3) * DD + d]; ++cnt; }
  }
  Cpart[(c * 8 + chunk) * DD + d] = acc;
  if (d == 0) cntPart[c * 8 + chunk] = (float)cnt;
}

__global__ __launch_bounds__(128) void k_csum2(const float* __restrict__ Cpart,
                                               const float* __restrict__ cntPart,
                                               float* __restrict__ C,
                                               float* __restrict__ cntN) {
  const int c = blockIdx.x, d = threadIdx.x;
  float s = 0.f;
  for (int k = 0; k < 8; ++k) s += Cpart[(c * 8 + k) * DD + d];
  C[c * DD + d] = s;
  if (d == 0) {
    float n = 0.f;
    for (int k = 0; k < 8; ++k) n += cntPart[c * 8 + k];
    cntN[c] = n;
  }
}

// ---------------- per-row con & cnt (fp32 exact): wave per row ----------------
__global__ __launch_bounds__(256) void k_con(const float* __restrict__ z,
                                             const int* __restrict__ labels,
                                             const float* __restrict__ C,
                                             const float* __restrict__ cntN,
                                             float2* __restrict__ conw) {
  const int lane = threadIdx.x & 63, wid = threadIdx.x >> 6;
  for (int it = 0; it < 16; ++it) {
    int row = blockIdx.x * 64 + wid * 16 + it;
    int y = labels[row];
    float2 zv = *reinterpret_cast<const float2*>(z + row * DD + lane * 2);
    float2 cv = *reinterpret_cast<const float2*>(C + y * DD + lane * 2);
    float d1 = zv.x * cv.x + zv.y * cv.y;   // z_i . C_y
    float d2 = zv.x * zv.x + zv.y * zv.y;   // |z_i|^2
#pragma unroll
    for (int off = 32; off >= 1; off >>= 1) {
      d1 += __shfl_xor(d1, off);
      d2 += __shfl_xor(d2, off);
    }
    if (lane == 0) {
      float n = cntN[y] - 1.0f;
      float cw = (n > 0.5f) ? (d1 - d2) * 10.0f / n : 0.0f;
      conw[row] = make_float2(cw, n);
    }
  }
}

// ---------------- kernel 2: fused Gram + online log2-LSE ----------------
template<bool HD>
__device__ __forceinline__ void iter_step(const unsigned short* __restrict__ zb,
                                          const int* __restrict__ labels,
                                          int c0, int lr, int lg,
                                          const bf16x8v (&bfr)[2][4],
                                          const int (&i_)[2], const int (&labi)[2],
                                          float (&m)[2], float (&s)[2]) {
  int la[4][4];
#pragma unroll
  for (int st = 0; st < 4; ++st) {
    int4 lj = *reinterpret_cast<const int4*>(labels + c0 + st * 16 + lg * 4);
    la[st][0] = lj.x; la[st][1] = lj.y; la[st][2] = lj.z; la[st][3] = lj.w;
  }
  f32x4 acc[2][4];
#pragma unroll
  for (int st = 0; st < 4; ++st) {
    const unsigned short* ap = zb + (c0 + st * 16 + lr) * DD + lg * 8;
    bf16x8v a0 = *reinterpret_cast<const bf16x8v*>(ap);
    bf16x8v a1 = *reinterpret_cast<const bf16x8v*>(ap + 32);
    bf16x8v a2 = *reinterpret_cast<const bf16x8v*>(ap + 64);
    bf16x8v a3 = *reinterpret_cast<const bf16x8v*>(ap + 96);
#pragma unroll
    for (int t = 0; t < 2; ++t) {
      f32x4 a = (f32x4){0.f, 0.f, 0.f, 0.f};
      a = __builtin_amdgcn_mfma_f32_16x16x32_bf16(a0, bfr[t][0], a, 0, 0, 0);
      a = __builtin_amdgcn_mfma_f32_16x16x32_bf16(a1, bfr[t][1], a, 0, 0, 0);
      a = __builtin_amdgcn_mfma_f32_16x16x32_bf16(a2, bfr[t][2], a, 0, 0, 0);
      a = __builtin_amdgcn_mfma_f32_16x16x32_bf16(a3, bfr[t][3], a, 0, 0, 0);
      acc[t][st] = a;
    }
  }
#pragma unroll
  for (int t = 0; t < 2; ++t) {
    float v[16];
#pragma unroll
    for (int st = 0; st < 4; ++st) {
#pragma unroll
      for (int r = 0; r < 4; ++r) {
        float x2 = acc[t][st][r];                       // already log2-scaled
        float vv = (la[st][r] == labi[t]) ? x2 - 1.0f : x2; // + log2(0.5)
        if (HD) {
          int j = c0 + st * 16 + lg * 4 + r;
          vv = (j == i_[t]) ? NEG_BIG : vv;
        }
        v[st * 4 + r] = vv;
      }
    }
    // tree max
    float m8[8], m4[4], m2[2];
#pragma unroll
    for (int k = 0; k < 8; ++k) m8[k] = fmaxf(v[k], v[k + 8]);
#pragma unroll
    for (int k = 0; k < 4; ++k) m4[k] = fmaxf(m8[k], m8[k + 4]);
    m2[0] = fmaxf(m4[0], m4[2]); m2[1] = fmaxf(m4[1], m4[3]);
    float tm = fmaxf(m2[0], m2[1]);
    float mn = fmaxf(m[t], tm);
    // tree sum of exp2
    float e[16];
#pragma unroll
    for (int k = 0; k < 16; ++k) e[k] = exp2f(v[k] - mn);
#pragma unroll
    for (int k = 0; k < 8; ++k) e[k] += e[k + 8];
#pragma unroll
    for (int k = 0; k < 4; ++k) e[k] += e[k + 4];
    float ssum = (e[0] + e[1]) + (e[2] + e[3]);
    s[t] = fmaf(s[t], exp2f(m[t] - mn), ssum);
    m[t] = mn;
  }
}

__global__ __launch_bounds__(256, 4) void k_main(const unsigned short* __restrict__ zb,
                                                 const int* __restrict__ labels,
                                                 float2* __restrict__ partials,
                                                 int colsPerChunk) {
  const int lane = threadIdx.x & 63;
  const int wid  = threadIdx.x >> 6;
  const int lr = lane & 15, lg = lane >> 4;
  const int rowbase = blockIdx.x * 128 + wid * 32;
  const int cb = blockIdx.y;
  const int cStart = cb * colsPerChunk;
  const int cEnd   = cStart + colsPerChunk;

  bf16x8v bfr[2][4];
  int i_[2], labi[2];
#pragma unroll
  for (int t = 0; t < 2; ++t) {
    int row = rowbase + t * 16 + lr;
    i_[t] = row;
    labi[t] = labels[row];
#pragma unroll
    for (int ks = 0; ks < 4; ++ks)
      bfr[t][ks] = *reinterpret_cast<const bf16x8v*>(zb + row * DD + ks * 32 + lg * 8);
  }

  float m[2] = {M_INIT, M_INIT};
  float s[2] = {0.f, 0.f};

  for (int c0 = cStart; c0 < cEnd; c0 += 64) {
    bool hd = (c0 < rowbase + 32) && (rowbase < c0 + 64);
    if (hd) iter_step<true >(zb, labels, c0, lr, lg, bfr, i_, labi, m, s);
    else    iter_step<false>(zb, labels, c0, lr, lg, bfr, i_, labi, m, s);
  }

  // merge the 4 lane-groups (xor 16, 32)
#pragma unroll
  for (int off = 16; off <= 32; off <<= 1) {
#pragma unroll
    for (int t = 0; t < 2; ++t) {
      float mo = __shfl_xor(m[t], off);
      float so = __shfl_xor(s[t], off);
      float mn = fmaxf(m[t], mo);
      s[t] = s[t] * exp2f(m[t] - mn) + so * exp2f(mo - mn);
      m[t] = mn;
    }
  }
  if (lg == 0) {
#pragma unroll
    for (int t = 0; t < 2; ++t)
      partials[cb * NN + i_[t]] = make_float2(m[t], s[t]);
  }
}

// ---------------- final merge, stage 1: 4 threads per row ----------------
__global__ __launch_bounds__(256) void k_final1(const float2* __restrict__ partials,
                                                const float2* __restrict__ conw,
                                                float* __restrict__ bsum, int NC) {
  const int gt = blockIdx.x * 256 + threadIdx.x;
  const int row = gt >> 2, part = gt & 3;
  const int cpt = NC >> 2;
  float m = M_INIT, s = 0.f;
  for (int k = 0; k < cpt; ++k) {
    float2 p = partials[(part * cpt + k) * NN + row];
    float mn = fmaxf(m, p.x);
    s = s * exp2f(m - mn) + p.y * exp2f(p.x - mn);
    m = mn;
  }
#pragma unroll
  for (int off = 1; off <= 2; off <<= 1) {
    float mo = __shfl_xor(m, off);
    float so = __shfl_xor(s, off);
    float mn = fmaxf(m, mo);
    s = s * exp2f(m - mn) + so * exp2f(mo - mn);
    m = mn;
  }
  float rl = 0.f;
  if (part == 0) {
    float2 cw = conw[row];
    if (cw.y > 0.5f) rl = LN2 * (m + log2f(s)) - cw.x;
  }
#pragma unroll
  for (int off = 32; off >= 1; off >>= 1) rl += __shfl_xor(rl, off);
  __shared__ float sm[4];
  if ((threadIdx.x & 63) == 0) sm[threadIdx.x >> 6] = rl;
  __syncthreads();
  if (threadIdx.x == 0) bsum[blockIdx.x] = (sm[0] + sm[1]) + (sm[2] + sm[3]);
}

// ---------------- final merge, stage 2 ----------------
__global__ __launch_bounds__(128) void k_final2(const float* __restrict__ bsum,
                                                float* __restrict__ out) {
  float v = bsum[threadIdx.x];
#pragma unroll
  for (int off = 32; off >= 1; off >>= 1) v += __shfl_xor(v, off);
  __shared__ float t2[2];
  if ((threadIdx.x & 63) == 0) t2[threadIdx.x >> 6] = v;
  __syncthreads();
  if (threadIdx.x == 0) out[0] = (t2[0] + t2[1]) * (1.0f / (float)NN);
}

extern "C" void kernel_launch(void* const* d_in, const int* in_sizes, int n_in,
                              void* d_out, int out_size, void* d_ws, size_t ws_size,
                              hipStream_t stream) {
  const float* z      = (const float*)d_in[0];
  const int*   labels = (const int*)d_in[1];

  size_t off = 0;
  auto alloc = [&](size_t b) { size_t p = off; off = (off + b + 255) & ~(size_t)255; return p; };
  char* ws = (char*)d_ws;
  size_t o_zb      = alloc((size_t)NN * DD * 2);
  size_t o_Cpart   = alloc((size_t)NCLS * 8 * DD * 4);
  size_t o_cntPart = alloc((size_t)NCLS * 8 * 4);
  size_t o_C       = alloc((size_t)NCLS * DD * 4);
  size_t o_cntN    = alloc((size_t)NCLS * 4);
  size_t o_conw    = alloc((size_t)NN * 8);
  size_t o_bsum    = alloc(128 * 4);

  int NC = 32;
  while (NC > 4 && off + (size_t)NC * NN * 8 > ws_size) NC >>= 1;
  size_t o_part = alloc((size_t)NC * NN * 8);
  (void)o_part;

  unsigned short* zb  = (unsigned short*)(ws + o_zb);
  float* Cpart        = (float*)(ws + o_Cpart);
  float* cntPart      = (float*)(ws + o_cntPart);
  float* C            = (float*)(ws + o_C);
  float* cntN         = (float*)(ws + o_cntN);
  float2* conw        = (float2*)(ws + o_conw);
  float* bsum         = (float*)(ws + o_bsum);
  float2* partials    = (float2*)(ws + o_part);

  int colsPerChunk = NN / NC;

  hipLaunchKernelGGL(k_convert, dim3(NN * DD / 4 / 256), dim3(256), 0, stream, z, zb);
  hipLaunchKernelGGL(k_csum,    dim3(NCLS, 8), dim3(128), 0, stream, z, labels, Cpart, cntPart);
  hipLaunchKernelGGL(k_csum2,   dim3(NCLS),    dim3(128), 0, stream, Cpart, cntPart, C, cntN);
  hipLaunchKernelGGL(k_con,     dim3(NN / 64), dim3(256), 0, stream, z, labels, C, cntN, conw);
  hipLaunchKernelGGL(k_main,    dim3(NN / 128, NC), dim3(256), 0, stream, zb, labels, partials, colsPerChunk);
  hipLaunchKernelGGL(k_final1,  dim3(NN * 4 / 256), dim3(256), 0, stream, partials, conw, bsum, NC);
  hipLaunchKernelGGL(k_final2,  dim3(1), dim3(128), 0, stream, bsum, (float*)d_out);
}

// Round 3
// 56.087 us; speedup vs baseline: 2.2192x; 2.2192x over previous
//
#include <hip/hip_runtime.h>

#define NN 8192
#define DD 128
#define BR 128          // rows per block
#define BC 128          // cols per LDS tile
#define NC 8            // column chunks (grid.y)
#define CPC (NN / NC)   // 1024 cols per chunk
#define NT (CPC / BC)   // 8 tiles per block

typedef short bf16x8v __attribute__((ext_vector_type(8)));
typedef float f32x4  __attribute__((ext_vector_type(4)));

constexpr float SSCALE  = 3.7982825265208916f; // sqrt((1/T)*log2(e))
constexpr float LN2     = 0.6931471805599453f;
constexpr float NEG_BIG = -1.0e30f;
constexpr float M_INIT  = -3.0e38f;

// ---------------- kernel 1: fp32 -> bf16 (RNE), pre-scaled by sqrt(SCALE2) ----------------
__global__ __launch_bounds__(256) void k_convert(const float* __restrict__ z,
                                                 unsigned short* __restrict__ zb) {
  int i = blockIdx.x * blockDim.x + threadIdx.x; // one float4 per thread
  const float4 v = reinterpret_cast<const float4*>(z)[i];
  auto cvt = [](float f) -> unsigned short {
    unsigned u = __float_as_uint(f);
    unsigned r = (u + 0x7fffu + ((u >> 16) & 1u)) >> 16;
    return (unsigned short)r;
  };
  ushort4 o;
  o.x = cvt(v.x * SSCALE); o.y = cvt(v.y * SSCALE);
  o.z = cvt(v.z * SSCALE); o.w = cvt(v.w * SSCALE);
  reinterpret_cast<ushort4*>(zb)[i] = o;
}

// ---- async global->LDS staging of one 128x128 bf16 tile (32KB contiguous slab) ----
// LDS dest is linear (HW: wave-uniform base + lane*16). The XOR swizzle is applied
// on the GLOBAL source chunk index (rule #21: inverse-swz source + swz read).
__device__ __forceinline__ void stage_tile(const unsigned short* __restrict__ zb,
                                           int gc0, unsigned short* __restrict__ bufc,
                                           int tid) {
#pragma unroll
  for (int q = 0; q < 8; ++q) {
    int c = q * 256 + tid;          // 16B chunk index, 2048 total
    int r = c >> 4;                 // row within tile (0..127)
    int w = c & 15;                 // 16B slot within row
    int wsrc = w ^ (r & 7);         // inverse swizzle (XOR involution)
    const unsigned short* g = zb + ((size_t)(gc0 + r) << 7) + (wsrc << 3);
    __builtin_amdgcn_global_load_lds(
        (const __attribute__((address_space(1))) void*)(uintptr_t)g,
        (__attribute__((address_space(3))) void*)(unsigned)(uintptr_t)(bufc + (c << 3)),
        16, 0, 0);
  }
}

// ---------------- epilogue for one 128-col tile ----------------
template<bool HD>
__device__ __forceinline__ void epilogue(const f32x4 (&acc)[2][8], const int4 (&la)[8],
                                         const int (&labi)[2], const int (&ii_)[2],
                                         int lg, float (&m)[2], float (&s)[2],
                                         float (&con)[2], float (&cnt)[2]) {
#pragma unroll
  for (int t = 0; t < 2; ++t) {
    float x[32];
    float cacc = 0.f, nacc = 0.f;
#pragma unroll
    for (int st = 0; st < 8; ++st) {
      int lav[4] = {la[st].x, la[st].y, la[st].z, la[st].w};
#pragma unroll
      for (int r = 0; r < 4; ++r) {
        float v = acc[t][st][r];
        bool mt = (lav[r] == labi[t]);
        bool dg = false;
        if (HD) dg = ((st * 16 + lg * 4 + r) == ii_[t]);
        float wc = (mt && !dg) ? 1.0f : 0.0f;
        cacc = fmaf(v, wc, cacc);
        nacc += wc;
        float xl = mt ? v - 1.0f : v;   // +log2(0.5): 0.5*exp2(v) = exp2(v-1)
        if (HD) xl = dg ? NEG_BIG : xl; // exclude diagonal from max & sum
        x[st * 4 + r] = xl;
      }
    }
    con[t] += cacc;
    cnt[t] += nacc;
    // tree max over 32
    float m16[16], m8[8], m4[4];
#pragma unroll
    for (int k = 0; k < 16; ++k) m16[k] = fmaxf(x[k], x[k + 16]);
#pragma unroll
    for (int k = 0; k < 8; ++k)  m8[k]  = fmaxf(m16[k], m16[k + 8]);
#pragma unroll
    for (int k = 0; k < 4; ++k)  m4[k]  = fmaxf(m8[k], m8[k + 4]);
    float tm = fmaxf(fmaxf(m4[0], m4[1]), fmaxf(m4[2], m4[3]));
    float mn = fmaxf(m[t], tm);
    float resc = exp2f(m[t] - mn);
    float s0 = 0.f, s1 = 0.f, s2 = 0.f, s3 = 0.f;
#pragma unroll
    for (int k = 0; k < 32; k += 4) {
      s0 += exp2f(x[k + 0] - mn);
      s1 += exp2f(x[k + 1] - mn);
      s2 += exp2f(x[k + 2] - mn);
      s3 += exp2f(x[k + 3] - mn);
    }
    s[t] = fmaf(s[t], resc, (s0 + s1) + (s2 + s3));
    m[t] = mn;
  }
}

// ---------------- kernel 2: fused Gram + online log2-LSE, LDS double-buffered ----------------
__global__ __launch_bounds__(256, 2) void k_main(const unsigned short* __restrict__ zb,
                                                 const int* __restrict__ labels,
                                                 float4* __restrict__ partials) {
  __shared__ unsigned short lds_a[2][BC * DD];   // 2 x 32KB

  const int tid  = threadIdx.x;
  const int lane = tid & 63;
  const int wid  = tid >> 6;
  const int lr = lane & 15, lg = lane >> 4;
  const int rx = lr & 7;                         // read-swizzle key (row & 7)
  const int rowbase = blockIdx.x * BR;
  const int cb      = blockIdx.y;
  const int cStart  = cb * CPC;

  // hoisted B fragments (anchor rows)
  bf16x8v bfr[2][4];
  int i_[2], labi[2], ii_[2];
#pragma unroll
  for (int t = 0; t < 2; ++t) {
    int row = rowbase + wid * 32 + t * 16 + lr;
    i_[t] = row; ii_[t] = wid * 32 + t * 16 + lr;
    labi[t] = labels[row];
#pragma unroll
    for (int ks = 0; ks < 4; ++ks)
      bfr[t][ks] = *reinterpret_cast<const bf16x8v*>(zb + (size_t)row * DD + ks * 32 + lg * 8);
  }

  stage_tile(zb, cStart, lds_a[0], tid);
  __syncthreads();   // full drain: tile 0 resident

  float m[2] = {M_INIT, M_INIT}, s[2] = {0.f, 0.f};
  float con[2] = {0.f, 0.f}, cnt[2] = {0.f, 0.f};

  // precomputed swizzled 16B-slot offsets for the 4 K-steps (lane-constant)
  int woff[4];
#pragma unroll
  for (int ks = 0; ks < 4; ++ks) woff[ks] = ((ks * 4 + lg) ^ rx) << 3; // ushort offset

  int cur = 0;
  for (int tt = 0; tt < NT; ++tt) {
    const int c0 = cStart + tt * BC;
    if (tt + 1 < NT) stage_tile(zb, c0 + BC, lds_a[cur ^ 1], tid);

    int4 la[8];
#pragma unroll
    for (int st = 0; st < 8; ++st)
      la[st] = *reinterpret_cast<const int4*>(labels + c0 + st * 16 + lg * 4);

    const unsigned short* bufc = lds_a[cur];
    f32x4 acc[2][8];
#pragma unroll
    for (int st = 0; st < 8; ++st) {
      const unsigned short* rp = bufc + (st * 16 + lr) * DD;
      bf16x8v a0 = *reinterpret_cast<const bf16x8v*>(rp + woff[0]);
      bf16x8v a1 = *reinterpret_cast<const bf16x8v*>(rp + woff[1]);
      bf16x8v a2 = *reinterpret_cast<const bf16x8v*>(rp + woff[2]);
      bf16x8v a3 = *reinterpret_cast<const bf16x8v*>(rp + woff[3]);
#pragma unroll
      for (int t = 0; t < 2; ++t) {
        f32x4 a = (f32x4){0.f, 0.f, 0.f, 0.f};
        a = __builtin_amdgcn_mfma_f32_16x16x32_bf16(a0, bfr[t][0], a, 0, 0, 0);
        a = __builtin_amdgcn_mfma_f32_16x16x32_bf16(a1, bfr[t][1], a, 0, 0, 0);
        a = __builtin_amdgcn_mfma_f32_16x16x32_bf16(a2, bfr[t][2], a, 0, 0, 0);
        a = __builtin_amdgcn_mfma_f32_16x16x32_bf16(a3, bfr[t][3], a, 0, 0, 0);
        acc[t][st] = a;
      }
    }

    if (c0 == rowbase) epilogue<true >(acc, la, labi, ii_, lg, m, s, con, cnt);
    else               epilogue<false>(acc, la, labi, ii_, lg, m, s, con, cnt);

    __syncthreads();   // drains next-tile stage (vmcnt 0) + protects buffer reuse
    cur ^= 1;
  }

  // merge the 4 lane-groups (xor 16, 32)
#pragma unroll
  for (int off = 16; off <= 32; off <<= 1) {
#pragma unroll
    for (int t = 0; t < 2; ++t) {
      float mo = __shfl_xor(m[t], off);
      float so = __shfl_xor(s[t], off);
      float co = __shfl_xor(con[t], off);
      float no = __shfl_xor(cnt[t], off);
      float mn = fmaxf(m[t], mo);
      s[t] = s[t] * exp2f(m[t] - mn) + so * exp2f(mo - mn);
      m[t] = mn;
      con[t] += co;
      cnt[t] += no;
    }
  }
  if (lg == 0) {
#pragma unroll
    for (int t = 0; t < 2; ++t)
      partials[(size_t)cb * NN + i_[t]] = make_float4(m[t], s[t], con[t], cnt[t]);
  }
}

// ---------------- final merge, stage 1: one thread per row ----------------
__global__ __launch_bounds__(256) void k_final1(const float4* __restrict__ partials,
                                                float* __restrict__ bsum) {
  const int row = blockIdx.x * 256 + threadIdx.x;
  float m = M_INIT, s = 0.f, con = 0.f, cnt = 0.f;
#pragma unroll
  for (int c = 0; c < NC; ++c) {
    float4 p = partials[(size_t)c * NN + row];
    float mn = fmaxf(m, p.x);
    s = s * exp2f(m - mn) + p.y * exp2f(p.x - mn);
    m = mn; con += p.z; cnt += p.w;
  }
  float rl = (cnt > 0.5f) ? LN2 * (m + log2f(s) - con / cnt) : 0.f;
#pragma unroll
  for (int off = 32; off >= 1; off >>= 1) rl += __shfl_xor(rl, off);
  __shared__ float sm[4];
  if ((threadIdx.x & 63) == 0) sm[threadIdx.x >> 6] = rl;
  __syncthreads();
  if (threadIdx.x == 0) bsum[blockIdx.x] = (sm[0] + sm[1]) + (sm[2] + sm[3]);
}

// ---------------- final merge, stage 2 ----------------
__global__ __launch_bounds__(64) void k_final2(const float* __restrict__ bsum,
                                               float* __restrict__ out) {
  const int tid = threadIdx.x;
  float v = (tid < 32) ? bsum[tid] : 0.f;
#pragma unroll
  for (int off = 32; off >= 1; off >>= 1) v += __shfl_xor(v, off);
  if (tid == 0) out[0] = v * (1.0f / (float)NN);
}

extern "C" void kernel_launch(void* const* d_in, const int* in_sizes, int n_in,
                              void* d_out, int out_size, void* d_ws, size_t ws_size,
                              hipStream_t stream) {
  const float* z      = (const float*)d_in[0];
  const int*   labels = (const int*)d_in[1];

  char* ws = (char*)d_ws;
  unsigned short* zb = (unsigned short*)ws;                         // 2 MB
  float4* partials   = (float4*)(ws + (size_t)NN * DD * 2);         // NC*NN*16 = 1 MB
  float*  bsum       = (float*)(ws + (size_t)NN * DD * 2 + (size_t)NC * NN * 16);

  hipLaunchKernelGGL(k_convert, dim3(NN * DD / 4 / 256), dim3(256), 0, stream, z, zb);
  hipLaunchKernelGGL(k_main,    dim3(NN / BR, NC), dim3(256), 0, stream, zb, labels, partials);
  hipLaunchKernelGGL(k_final1,  dim3(NN / 256), dim3(256), 0, stream, partials, bsum);
  hipLaunchKernelGGL(k_final2,  dim3(1), dim3(64), 0, stream, bsum, (float*)d_out);
}